// Round 1
// baseline (1183.642 us; speedup 1.0000x reference)
//
#include <hip/hip_runtime.h>
#include <hip/hip_bf16.h>

#define N_NODES 50000
#define N_EDGES 800000

// ---------------------------------------------------------------------------
// init: zero edge counts and the pooled vector g
__global__ void k_init(int* __restrict__ cnt, float* __restrict__ g) {
    int i = blockIdx.x * blockDim.x + threadIdx.x;
    if (i < N_NODES) cnt[i] = 0;
    if (i < 256) g[i] = 0.0f;
}

// count in-degree (destination = col)
__global__ void k_count(const int* __restrict__ col, int* __restrict__ cnt) {
    int e = blockIdx.x * blockDim.x + threadIdx.x;
    if (e < N_EDGES) atomicAdd(&cnt[col[e]], 1);
}

// dinv = 1/sqrt(cnt + 1)  (+1 = self loop)
__global__ void k_dinv(const int* __restrict__ cnt, float* __restrict__ dinv) {
    int i = blockIdx.x * blockDim.x + threadIdx.x;
    if (i < N_NODES) dinv[i] = 1.0f / sqrtf((float)(cnt[i] + 1));
}

// single-block exclusive scan of cnt -> off[0..N], also init cursor
__global__ void k_scan(const int* __restrict__ cnt, int* __restrict__ off,
                       int* __restrict__ cursor) {
    const int T = 1024;
    const int CHUNK = (N_NODES + T - 1) / T; // 49
    __shared__ int part[T];
    int t = threadIdx.x;
    int lo = t * CHUNK;
    int hi = lo + CHUNK; if (hi > N_NODES) hi = N_NODES;
    int s = 0;
    for (int i = lo; i < hi; ++i) s += cnt[i];
    part[t] = s;
    __syncthreads();
    for (int d = 1; d < T; d <<= 1) {
        int v = 0;
        if (t >= d) v = part[t - d];
        __syncthreads();
        if (t >= d) part[t] += v;
        __syncthreads();
    }
    int run = part[t] - s; // exclusive base
    for (int i = lo; i < hi; ++i) {
        off[i] = run;
        cursor[i] = run;
        run += cnt[i];
    }
    if (t == T - 1) off[N_NODES] = run; // == N_EDGES
}

// fill CSR payload: per edge, slot = cursor[col]++; store source row + dinv[row]
__global__ void k_fill(const int* __restrict__ row, const int* __restrict__ col,
                       const float* __restrict__ dinv, int* __restrict__ cursor,
                       int* __restrict__ erow, float* __restrict__ ew) {
    int e = blockIdx.x * blockDim.x + threadIdx.x;
    if (e >= N_EDGES) return;
    int v = col[e];
    int p = atomicAdd(&cursor[v], 1);
    int r = row[e];
    erow[p] = r;
    ew[p] = dinv[r];
}

// aggregation: out[v] = dinv[v] * ( x[v]*dinv[v] + sum_j x[r_j]*dinv[r_j] )
// one block per node, DIM threads (one feature each)
template <int DIM, int BIAS_RELU>
__global__ void k_agg(const float* __restrict__ x, const int* __restrict__ off,
                      const int* __restrict__ erow, const float* __restrict__ ew,
                      const float* __restrict__ dinv, const float* __restrict__ bias,
                      float* __restrict__ out) {
    int v = blockIdx.x;
    int f = threadIdx.x;
    float dv = dinv[v];
    float acc = x[(size_t)v * DIM + f] * dv;
    int s = off[v], e = off[v + 1];
    for (int j = s; j < e; ++j) {
        int r = erow[j];
        float w = ew[j];
        acc += x[(size_t)r * DIM + f] * w;
    }
    acc *= dv;
    if (BIAS_RELU) acc = fmaxf(acc + bias[f], 0.0f);
    out[(size_t)v * DIM + f] = acc;
}

// fp32 GEMM: C[M,N] = A[M,K] @ W[K,N] (+bias) (relu). 64x64 tile, BK=16,
// 256 threads, 4x4 per thread.
template <int BIAS, int RELU>
__global__ __launch_bounds__(256) void k_gemm(
    const float* __restrict__ A, const float* __restrict__ W,
    const float* __restrict__ bias, float* __restrict__ C,
    int M, int K, int N) {
    __shared__ float As[16][64]; // [k][m]
    __shared__ float Bs[16][64]; // [k][n]
    int tid = threadIdx.x;
    int tx = tid & 15, ty = tid >> 4;
    int bm = blockIdx.x * 64;
    int bn = blockIdx.y * 64;

    float acc[4][4];
#pragma unroll
    for (int i = 0; i < 4; ++i)
#pragma unroll
        for (int j = 0; j < 4; ++j) acc[i][j] = 0.0f;

    int atr = tid >> 2;          // 0..63 tile row
    int atc = (tid & 3) * 4;     // 0,4,8,12 tile col (k)
    int wtr = tid >> 4;          // 0..15 (k)
    int wtc = (tid & 15) * 4;    // 0..60 (n)

    for (int k0 = 0; k0 < K; k0 += 16) {
        float4 av;
        int ar = bm + atr;
        if (ar < M) av = *(const float4*)&A[(size_t)ar * K + k0 + atc];
        else av = make_float4(0.f, 0.f, 0.f, 0.f);
        As[atc + 0][atr] = av.x;
        As[atc + 1][atr] = av.y;
        As[atc + 2][atr] = av.z;
        As[atc + 3][atr] = av.w;
        float4 wv = *(const float4*)&W[(size_t)(k0 + wtr) * N + bn + wtc];
        *(float4*)&Bs[wtr][wtc] = wv;
        __syncthreads();
#pragma unroll
        for (int k = 0; k < 16; ++k) {
            float4 a = *(const float4*)&As[k][ty * 4];
            float4 b = *(const float4*)&Bs[k][tx * 4];
            acc[0][0] += a.x * b.x; acc[0][1] += a.x * b.y; acc[0][2] += a.x * b.z; acc[0][3] += a.x * b.w;
            acc[1][0] += a.y * b.x; acc[1][1] += a.y * b.y; acc[1][2] += a.y * b.z; acc[1][3] += a.y * b.w;
            acc[2][0] += a.z * b.x; acc[2][1] += a.z * b.y; acc[2][2] += a.z * b.z; acc[2][3] += a.z * b.w;
            acc[3][0] += a.w * b.x; acc[3][1] += a.w * b.y; acc[3][2] += a.w * b.z; acc[3][3] += a.w * b.w;
        }
        __syncthreads();
    }

    float4 bv = make_float4(0.f, 0.f, 0.f, 0.f);
    if (BIAS) bv = *(const float4*)&bias[bn + tx * 4];
#pragma unroll
    for (int i = 0; i < 4; ++i) {
        int r = bm + ty * 4 + i;
        if (r < M) {
            float4 o;
            o.x = acc[i][0] + bv.x;
            o.y = acc[i][1] + bv.y;
            o.z = acc[i][2] + bv.z;
            o.w = acc[i][3] + bv.w;
            if (RELU) {
                o.x = fmaxf(o.x, 0.f); o.y = fmaxf(o.y, 0.f);
                o.z = fmaxf(o.z, 0.f); o.w = fmaxf(o.w, 0.f);
            }
            *(float4*)&C[(size_t)r * N + bn + tx * 4] = o;
        }
    }
}

// column partial-sums of h3 [N_NODES x 256] into g via one atomic per block/col
__global__ void k_colsum(const float* __restrict__ h, float* __restrict__ g) {
    int c = threadIdx.x; // 256
    int r0 = blockIdx.x * 256;
    int r1 = r0 + 256; if (r1 > N_NODES) r1 = N_NODES;
    float acc = 0.0f;
    for (int r = r0; r < r1; ++r) acc += h[(size_t)r * 256 + c];
    atomicAdd(&g[c], acc);
}

// tiny MLP: g/N -> 128 -> 64 -> 1
__global__ void k_mlp(const float* __restrict__ g,
                      const float* __restrict__ Wf1, const float* __restrict__ bf1,
                      const float* __restrict__ Wf2, const float* __restrict__ bf2,
                      const float* __restrict__ Wf3, const float* __restrict__ bf3,
                      float* __restrict__ out) {
    __shared__ float s0[256], s1[128], s2[64];
    int t = threadIdx.x; // 256
    s0[t] = g[t] * (1.0f / (float)N_NODES);
    __syncthreads();
    if (t < 128) {
        float a = bf1[t];
        for (int k = 0; k < 256; ++k) a += s0[k] * Wf1[k * 128 + t];
        s1[t] = fmaxf(a, 0.0f);
    }
    __syncthreads();
    if (t < 64) {
        float a = bf2[t];
        for (int k = 0; k < 128; ++k) a += s1[k] * Wf2[k * 64 + t];
        s2[t] = fmaxf(a, 0.0f);
    }
    __syncthreads();
    if (t == 0) {
        float a = bf3[0];
        for (int k = 0; k < 64; ++k) a += s2[k] * Wf3[k];
        out[0] = a;
    }
}

extern "C" void kernel_launch(void* const* d_in, const int* in_sizes, int n_in,
                              void* d_out, int out_size, void* d_ws, size_t ws_size,
                              hipStream_t stream) {
    const float* x  = (const float*)d_in[0];
    const int* ei   = (const int*)d_in[1];   // [2, E]: row = ei[0..E), col = ei[E..2E)
    const float* W1 = (const float*)d_in[2];
    const float* b1 = (const float*)d_in[3];
    const float* W2 = (const float*)d_in[4];
    const float* b2 = (const float*)d_in[5];
    const float* W3 = (const float*)d_in[6];
    const float* b3 = (const float*)d_in[7];
    const float* Wf1 = (const float*)d_in[8];
    const float* bf1 = (const float*)d_in[9];
    const float* Wf2 = (const float*)d_in[10];
    const float* bf2 = (const float*)d_in[11];
    const float* Wf3 = (const float*)d_in[12];
    const float* bf3 = (const float*)d_in[13];
    float* out = (float*)d_out;

    // bump allocator over d_ws
    char* p = (char*)d_ws;
    auto alloc = [&](size_t bytes) {
        void* r = (void*)p;
        p += (bytes + 255) & ~((size_t)255);
        return r;
    };
    int*   cnt    = (int*)  alloc(N_NODES * sizeof(int));
    int*   off    = (int*)  alloc((N_NODES + 1) * sizeof(int));
    int*   cursor = (int*)  alloc(N_NODES * sizeof(int));
    float* dinv   = (float*)alloc(N_NODES * sizeof(float));
    int*   erow   = (int*)  alloc(N_EDGES * sizeof(int));
    float* ew     = (float*)alloc(N_EDGES * sizeof(float));
    float* g      = (float*)alloc(256 * sizeof(float));
    float* R1     = (float*)alloc((size_t)N_NODES * 256 * sizeof(float)); // t0, t1, h3
    float* R2     = (float*)alloc((size_t)N_NODES * 256 * sizeof(float)); // h1, t2
    float* R3     = (float*)alloc((size_t)N_NODES * 512 * sizeof(float)); // h2

    const int* row = ei;
    const int* col = ei + N_EDGES;

    const int NB = (N_NODES + 255) / 256;   // 196
    const int EB = (N_EDGES + 255) / 256;   // 3125

    k_init<<<NB, 256, 0, stream>>>(cnt, g);
    k_count<<<EB, 256, 0, stream>>>(col, cnt);
    k_dinv<<<NB, 256, 0, stream>>>(cnt, dinv);
    k_scan<<<1, 1024, 0, stream>>>(cnt, off, cursor);
    k_fill<<<EB, 256, 0, stream>>>(row, col, dinv, cursor, erow, ew);

    const int M = N_NODES;
    const int MB = (M + 63) / 64; // 782

    // conv1: t0 = agg(x) [N,128]; h1 = relu(t0@W1 + b1) [N,256]
    k_agg<128, 0><<<N_NODES, 128, 0, stream>>>(x, off, erow, ew, dinv, nullptr, R1);
    {
        dim3 grid(MB, 256 / 64);
        k_gemm<1, 1><<<grid, 256, 0, stream>>>(R1, W1, b1, R2, M, 128, 256);
    }
    // conv2: t1 = agg(h1) [N,256]; h2 = relu(t1@W2 + b2) [N,512]
    k_agg<256, 0><<<N_NODES, 256, 0, stream>>>(R2, off, erow, ew, dinv, nullptr, R1);
    {
        dim3 grid(MB, 512 / 64);
        k_gemm<1, 1><<<grid, 256, 0, stream>>>(R1, W2, b2, R3, M, 256, 512);
    }
    // conv3: t2 = h2@W3 [N,256]; h3 = relu(agg(t2) + b3)
    {
        dim3 grid(MB, 256 / 64);
        k_gemm<0, 0><<<grid, 256, 0, stream>>>(R3, W3, nullptr, R2, M, 512, 256);
    }
    k_agg<256, 1><<<N_NODES, 256, 0, stream>>>(R2, off, erow, ew, dinv, b3, R1);

    // pooling + MLP
    k_colsum<<<NB, 256, 0, stream>>>(R1, g);
    k_mlp<<<1, 256, 0, stream>>>(g, Wf1, bf1, Wf2, bf2, Wf3, bf3, out);
}

// Round 2
// 1040.262 us; speedup vs baseline: 1.1378x; 1.1378x over previous
//
#include <hip/hip_runtime.h>
#include <hip/hip_bf16.h>

#define N_NODES 50000
#define N_EDGES 800000

// ---------------------------------------------------------------------------
__global__ void k_init(int* __restrict__ cnt, float* __restrict__ g) {
    int i = blockIdx.x * blockDim.x + threadIdx.x;
    if (i < N_NODES) cnt[i] = 0;
    if (i < 256) g[i] = 0.0f;
}

__global__ void k_count(const int* __restrict__ col, int* __restrict__ cnt) {
    int e = blockIdx.x * blockDim.x + threadIdx.x;
    if (e < N_EDGES) atomicAdd(&cnt[col[e]], 1);
}

__global__ void k_dinv(const int* __restrict__ cnt, float* __restrict__ dinv) {
    int i = blockIdx.x * blockDim.x + threadIdx.x;
    if (i < N_NODES) dinv[i] = 1.0f / sqrtf((float)(cnt[i] + 1));
}

// single-block exclusive scan of cnt -> off[0..N], also init cursor
__global__ void k_scan(const int* __restrict__ cnt, int* __restrict__ off,
                       int* __restrict__ cursor) {
    const int T = 1024;
    const int CHUNK = (N_NODES + T - 1) / T; // 49
    __shared__ int part[T];
    int t = threadIdx.x;
    int lo = t * CHUNK;
    int hi = lo + CHUNK; if (hi > N_NODES) hi = N_NODES;
    int s = 0;
    for (int i = lo; i < hi; ++i) s += cnt[i];
    part[t] = s;
    __syncthreads();
    for (int d = 1; d < T; d <<= 1) {
        int v = 0;
        if (t >= d) v = part[t - d];
        __syncthreads();
        if (t >= d) part[t] += v;
        __syncthreads();
    }
    int run = part[t] - s; // exclusive base
    for (int i = lo; i < hi; ++i) {
        off[i] = run;
        cursor[i] = run;
        run += cnt[i];
    }
    if (t == T - 1) off[N_NODES] = run;
}

// fill CSR payload packed as int2 {src_row, bits(dinv[src])}
__global__ void k_fill(const int* __restrict__ row, const int* __restrict__ col,
                       const float* __restrict__ dinv, int* __restrict__ cursor,
                       int2* __restrict__ epack) {
    int e = blockIdx.x * blockDim.x + threadIdx.x;
    if (e >= N_EDGES) return;
    int v = col[e];
    int p = atomicAdd(&cursor[v], 1);
    int r = row[e];
    epack[p] = make_int2(r, __float_as_int(dinv[r]));
}

// aggregation: out[v] = dinv[v] * ( x[v]*dinv[v] + sum_j x[r_j]*dinv[r_j] )
// DIM/4 lanes per node, float4 per lane, packed 8B edge loads.
template <int DIM, int BIAS_RELU>
__global__ __launch_bounds__(256) void k_agg4(
    const float* __restrict__ x, const int* __restrict__ off,
    const int2* __restrict__ epack, const float* __restrict__ dinv,
    const float* __restrict__ bias, float* __restrict__ out, int nnodes) {
    const int LPN = DIM / 4;        // lanes per node
    const int NPB = 256 / LPN;      // nodes per block
    int v = blockIdx.x * NPB + threadIdx.x / LPN;
    if (v >= nnodes) return;
    int f = (threadIdx.x % LPN) * 4;
    float dv = dinv[v];
    float4 xv = *(const float4*)&x[(size_t)v * DIM + f];
    float4 acc;
    acc.x = xv.x * dv; acc.y = xv.y * dv; acc.z = xv.z * dv; acc.w = xv.w * dv;
    int s = off[v], e = off[v + 1];
    for (int j = s; j < e; ++j) {
        int2 p = epack[j];
        int r = p.x;
        float w = __int_as_float(p.y);
        float4 xr = *(const float4*)&x[(size_t)r * DIM + f];
        acc.x += xr.x * w; acc.y += xr.y * w; acc.z += xr.z * w; acc.w += xr.w * w;
    }
    acc.x *= dv; acc.y *= dv; acc.z *= dv; acc.w *= dv;
    if (BIAS_RELU) {
        float4 bv = *(const float4*)&bias[f];
        acc.x = fmaxf(acc.x + bv.x, 0.f);
        acc.y = fmaxf(acc.y + bv.y, 0.f);
        acc.z = fmaxf(acc.z + bv.z, 0.f);
        acc.w = fmaxf(acc.w + bv.w, 0.f);
    }
    *(float4*)&out[(size_t)v * DIM + f] = acc;
}

// fp32 GEMM: C[M,N] = A[M,K] @ W[K,N] (+bias)(relu). 128x128 tile, BK=16,
// 256 threads, 8x8 per thread in split halves (rows {ty*4, 64+ty*4},
// cols {tx*4, 64+tx*4}) -> LDS reads are broadcast / 2-way only (free).
template <int BIAS, int RELU>
__global__ __launch_bounds__(256, 2) void k_gemm(
    const float* __restrict__ A, const float* __restrict__ W,
    const float* __restrict__ bias, float* __restrict__ C,
    int M, int K, int N) {
    __shared__ float As[16][128]; // [k][m]
    __shared__ float Bs[16][128]; // [k][n]
    int tid = threadIdx.x;
    int tx = tid & 15, ty = tid >> 4;
    int bm = blockIdx.x * 128;
    int bn = blockIdx.y * 128;

    float acc[8][8] = {};

    // A staging: thread -> row am=tid>>1 (0..127), k-offset ak=(tid&1)*8
    int am = tid >> 1;
    int ak = (tid & 1) * 8;
    const float* Aptr = A + (size_t)(bm + am) * K + ak;
    bool arow_ok = (bm + am) < M;
    // B staging: thread -> k-row bk=tid>>4 (0..15), col bc=(tid&15)*8
    int bk = tid >> 4;
    int bc = (tid & 15) * 8;
    const float* Wptr = W + (size_t)bk * N + bn + bc;

    for (int k0 = 0; k0 < K; k0 += 16) {
        float4 a0 = make_float4(0.f, 0.f, 0.f, 0.f), a1 = a0;
        if (arow_ok) {
            a0 = *(const float4*)(Aptr + k0);
            a1 = *(const float4*)(Aptr + k0 + 4);
        }
        float4 w0 = *(const float4*)(Wptr + (size_t)k0 * N);
        float4 w1 = *(const float4*)(Wptr + (size_t)k0 * N + 4);
        __syncthreads(); // previous tile fully consumed before overwrite
        As[ak + 0][am] = a0.x; As[ak + 1][am] = a0.y;
        As[ak + 2][am] = a0.z; As[ak + 3][am] = a0.w;
        As[ak + 4][am] = a1.x; As[ak + 5][am] = a1.y;
        As[ak + 6][am] = a1.z; As[ak + 7][am] = a1.w;
        *(float4*)&Bs[bk][bc] = w0;
        *(float4*)&Bs[bk][bc + 4] = w1;
        __syncthreads();
#pragma unroll
        for (int k = 0; k < 16; ++k) {
            float4 aA = *(const float4*)&As[k][ty * 4];
            float4 aB = *(const float4*)&As[k][64 + ty * 4];
            float4 bA = *(const float4*)&Bs[k][tx * 4];
            float4 bB = *(const float4*)&Bs[k][64 + tx * 4];
            float av[8] = {aA.x, aA.y, aA.z, aA.w, aB.x, aB.y, aB.z, aB.w};
            float bv[8] = {bA.x, bA.y, bA.z, bA.w, bB.x, bB.y, bB.z, bB.w};
#pragma unroll
            for (int i = 0; i < 8; ++i)
#pragma unroll
                for (int j = 0; j < 8; ++j)
                    acc[i][j] += av[i] * bv[j];
        }
    }

    float4 bv0 = make_float4(0.f, 0.f, 0.f, 0.f), bv1 = bv0;
    if (BIAS) {
        bv0 = *(const float4*)&bias[bn + tx * 4];
        bv1 = *(const float4*)&bias[bn + 64 + tx * 4];
    }
#pragma unroll
    for (int h = 0; h < 2; ++h) {
#pragma unroll
        for (int i = 0; i < 4; ++i) {
            int r = bm + h * 64 + ty * 4 + i;
            if (r < M) {
                float* crow = &C[(size_t)r * N + bn];
                float4 o0, o1;
                o0.x = acc[h * 4 + i][0] + bv0.x;
                o0.y = acc[h * 4 + i][1] + bv0.y;
                o0.z = acc[h * 4 + i][2] + bv0.z;
                o0.w = acc[h * 4 + i][3] + bv0.w;
                o1.x = acc[h * 4 + i][4] + bv1.x;
                o1.y = acc[h * 4 + i][5] + bv1.y;
                o1.z = acc[h * 4 + i][6] + bv1.z;
                o1.w = acc[h * 4 + i][7] + bv1.w;
                if (RELU) {
                    o0.x = fmaxf(o0.x, 0.f); o0.y = fmaxf(o0.y, 0.f);
                    o0.z = fmaxf(o0.z, 0.f); o0.w = fmaxf(o0.w, 0.f);
                    o1.x = fmaxf(o1.x, 0.f); o1.y = fmaxf(o1.y, 0.f);
                    o1.z = fmaxf(o1.z, 0.f); o1.w = fmaxf(o1.w, 0.f);
                }
                *(float4*)&crow[tx * 4] = o0;
                *(float4*)&crow[64 + tx * 4] = o1;
            }
        }
    }
}

// column partial-sums of h3 [N_NODES x 256] into g
__global__ void k_colsum(const float* __restrict__ h, float* __restrict__ g) {
    int c = threadIdx.x; // 256
    int r0 = blockIdx.x * 256;
    int r1 = r0 + 256; if (r1 > N_NODES) r1 = N_NODES;
    float acc = 0.0f;
    for (int r = r0; r < r1; ++r) acc += h[(size_t)r * 256 + c];
    atomicAdd(&g[c], acc);
}

// tiny MLP: g/N -> 128 -> 64 -> 1
__global__ void k_mlp(const float* __restrict__ g,
                      const float* __restrict__ Wf1, const float* __restrict__ bf1,
                      const float* __restrict__ Wf2, const float* __restrict__ bf2,
                      const float* __restrict__ Wf3, const float* __restrict__ bf3,
                      float* __restrict__ out) {
    __shared__ float s0[256], s1[128], s2[64];
    int t = threadIdx.x; // 256
    s0[t] = g[t] * (1.0f / (float)N_NODES);
    __syncthreads();
    if (t < 128) {
        float a = bf1[t];
        for (int k = 0; k < 256; ++k) a += s0[k] * Wf1[k * 128 + t];
        s1[t] = fmaxf(a, 0.0f);
    }
    __syncthreads();
    if (t < 64) {
        float a = bf2[t];
        for (int k = 0; k < 128; ++k) a += s1[k] * Wf2[k * 64 + t];
        s2[t] = fmaxf(a, 0.0f);
    }
    __syncthreads();
    if (t == 0) {
        float a = bf3[0];
        for (int k = 0; k < 64; ++k) a += s2[k] * Wf3[k];
        out[0] = a;
    }
}

extern "C" void kernel_launch(void* const* d_in, const int* in_sizes, int n_in,
                              void* d_out, int out_size, void* d_ws, size_t ws_size,
                              hipStream_t stream) {
    const float* x  = (const float*)d_in[0];
    const int* ei   = (const int*)d_in[1];
    const float* W1 = (const float*)d_in[2];
    const float* b1 = (const float*)d_in[3];
    const float* W2 = (const float*)d_in[4];
    const float* b2 = (const float*)d_in[5];
    const float* W3 = (const float*)d_in[6];
    const float* b3 = (const float*)d_in[7];
    const float* Wf1 = (const float*)d_in[8];
    const float* bf1 = (const float*)d_in[9];
    const float* Wf2 = (const float*)d_in[10];
    const float* bf2 = (const float*)d_in[11];
    const float* Wf3 = (const float*)d_in[12];
    const float* bf3 = (const float*)d_in[13];
    float* out = (float*)d_out;

    char* p = (char*)d_ws;
    auto alloc = [&](size_t bytes) {
        void* r = (void*)p;
        p += (bytes + 255) & ~((size_t)255);
        return r;
    };
    int*   cnt    = (int*)  alloc(N_NODES * sizeof(int));
    int*   off    = (int*)  alloc((N_NODES + 1) * sizeof(int));
    int*   cursor = (int*)  alloc(N_NODES * sizeof(int));
    float* dinv   = (float*)alloc(N_NODES * sizeof(float));
    int2*  epack  = (int2*) alloc((size_t)N_EDGES * sizeof(int2));
    float* g      = (float*)alloc(256 * sizeof(float));
    float* R1     = (float*)alloc((size_t)N_NODES * 256 * sizeof(float));
    float* R2     = (float*)alloc((size_t)N_NODES * 256 * sizeof(float));
    float* R3     = (float*)alloc((size_t)N_NODES * 512 * sizeof(float));

    const int* row = ei;
    const int* col = ei + N_EDGES;

    const int NB = (N_NODES + 255) / 256;
    const int EB = (N_EDGES + 255) / 256;

    k_init<<<NB, 256, 0, stream>>>(cnt, g);
    k_count<<<EB, 256, 0, stream>>>(col, cnt);
    k_dinv<<<NB, 256, 0, stream>>>(cnt, dinv);
    k_scan<<<1, 1024, 0, stream>>>(cnt, off, cursor);
    k_fill<<<EB, 256, 0, stream>>>(row, col, dinv, cursor, epack);

    const int M = N_NODES;
    const int MB = (M + 127) / 128; // 391

    // conv1: t0 = agg(x) [N,128]; h1 = relu(t0@W1 + b1) [N,256]
    k_agg4<128, 0><<<(N_NODES + 7) / 8, 256, 0, stream>>>(x, off, epack, dinv, nullptr, R1, N_NODES);
    {
        dim3 grid(MB, 256 / 128);
        k_gemm<1, 1><<<grid, 256, 0, stream>>>(R1, W1, b1, R2, M, 128, 256);
    }
    // conv2: t1 = agg(h1) [N,256]; h2 = relu(t1@W2 + b2) [N,512]
    k_agg4<256, 0><<<(N_NODES + 3) / 4, 256, 0, stream>>>(R2, off, epack, dinv, nullptr, R1, N_NODES);
    {
        dim3 grid(MB, 512 / 128);
        k_gemm<1, 1><<<grid, 256, 0, stream>>>(R1, W2, b2, R3, M, 256, 512);
    }
    // conv3: t2 = h2@W3 [N,256]; h3 = relu(agg(t2) + b3)
    {
        dim3 grid(MB, 256 / 128);
        k_gemm<0, 0><<<grid, 256, 0, stream>>>(R3, W3, nullptr, R2, M, 512, 256);
    }
    k_agg4<256, 1><<<(N_NODES + 3) / 4, 256, 0, stream>>>(R2, off, epack, dinv, b3, R1, N_NODES);

    // pooling + MLP
    k_colsum<<<NB, 256, 0, stream>>>(R1, g);
    k_mlp<<<1, 256, 0, stream>>>(g, Wf1, bf1, Wf2, bf2, Wf3, bf3, out);
}

// Round 3
// 868.807 us; speedup vs baseline: 1.3624x; 1.1973x over previous
//
#include <hip/hip_runtime.h>
#include <hip/hip_bf16.h>

#define N_NODES 50000
#define N_EDGES 800000

typedef short short8 __attribute__((ext_vector_type(8)));
typedef float floatx4 __attribute__((ext_vector_type(4)));
typedef unsigned short ushort4v __attribute__((ext_vector_type(4)));

// ---- bf16 helpers (RNE) ---------------------------------------------------
__device__ __forceinline__ unsigned short f2bf(float f) {
    unsigned u = __float_as_uint(f);
    unsigned r = (u + 0x7fff + ((u >> 16) & 1)) >> 16;
    return (unsigned short)r;
}
__device__ __forceinline__ float bf2f(unsigned short h) {
    return __uint_as_float(((unsigned)h) << 16);
}

// async global->LDS, 16B per lane; lds dest = wave-uniform base + lane*16
__device__ __forceinline__ void gload16(const void* gp, void* lp) {
    __builtin_amdgcn_global_load_lds(
        (const __attribute__((address_space(1))) unsigned int*)gp,
        (__attribute__((address_space(3))) unsigned int*)lp,
        16, 0, 0);
}

// ---------------------------------------------------------------------------
__global__ void k_init(int* __restrict__ cnt, float* __restrict__ g) {
    int i = blockIdx.x * blockDim.x + threadIdx.x;
    if (i < N_NODES) cnt[i] = 0;
    if (i < 256) g[i] = 0.0f;
}

__global__ void k_count(const int* __restrict__ col, int* __restrict__ cnt) {
    int e = blockIdx.x * blockDim.x + threadIdx.x;
    if (e < N_EDGES) atomicAdd(&cnt[col[e]], 1);
}

__global__ void k_dinv(const int* __restrict__ cnt, float* __restrict__ dinv) {
    int i = blockIdx.x * blockDim.x + threadIdx.x;
    if (i < N_NODES) dinv[i] = 1.0f / sqrtf((float)(cnt[i] + 1));
}

__global__ void k_scan(const int* __restrict__ cnt, int* __restrict__ off,
                       int* __restrict__ cursor) {
    const int T = 1024;
    const int CHUNK = (N_NODES + T - 1) / T; // 49
    __shared__ int part[T];
    int t = threadIdx.x;
    int lo = t * CHUNK;
    int hi = lo + CHUNK; if (hi > N_NODES) hi = N_NODES;
    int s = 0;
    for (int i = lo; i < hi; ++i) s += cnt[i];
    part[t] = s;
    __syncthreads();
    for (int d = 1; d < T; d <<= 1) {
        int v = 0;
        if (t >= d) v = part[t - d];
        __syncthreads();
        if (t >= d) part[t] += v;
        __syncthreads();
    }
    int run = part[t] - s;
    for (int i = lo; i < hi; ++i) {
        off[i] = run;
        cursor[i] = run;
        run += cnt[i];
    }
    if (t == T - 1) off[N_NODES] = run;
}

__global__ void k_fill(const int* __restrict__ row, const int* __restrict__ col,
                       const float* __restrict__ dinv, int* __restrict__ cursor,
                       int2* __restrict__ epack) {
    int e = blockIdx.x * blockDim.x + threadIdx.x;
    if (e >= N_EDGES) return;
    int v = col[e];
    int p = atomicAdd(&cursor[v], 1);
    int r = row[e];
    epack[p] = make_int2(r, __float_as_int(dinv[r]));
}

// convert W [K][N] fp32 -> transposed split bf16 WT{h,l} [N][K]
__global__ void k_prepW(const float* __restrict__ W,
                        unsigned short* __restrict__ Th,
                        unsigned short* __restrict__ Tl, int K, int N) {
    int idx = blockIdx.x * blockDim.x + threadIdx.x;
    if (idx >= K * N) return;
    int n = idx / K, k = idx - n * K;
    float v = W[(size_t)k * N + n];
    unsigned short h = f2bf(v);
    Th[idx] = h;
    Tl[idx] = f2bf(v - bf2f(h));
}

// aggregation: out[v] = dinv[v] * ( x[v]*dinv[v] + sum_j x[r_j]*dinv[r_j] )
// MODE 0: fp32 out + bias + relu;  MODE 1: split bf16 out (hi/lo)
template <int DIM, int MODE>
__global__ __launch_bounds__(256) void k_agg4(
    const float* __restrict__ x, const int* __restrict__ off,
    const int2* __restrict__ epack, const float* __restrict__ dinv,
    const float* __restrict__ bias, float* __restrict__ outf,
    unsigned short* __restrict__ outh, unsigned short* __restrict__ outl,
    int nnodes) {
    const int LPN = DIM / 4;
    const int NPB = 256 / LPN;
    int v = blockIdx.x * NPB + threadIdx.x / LPN;
    if (v >= nnodes) return;
    int f = (threadIdx.x % LPN) * 4;
    float dv = dinv[v];
    float4 xv = *(const float4*)&x[(size_t)v * DIM + f];
    float4 acc;
    acc.x = xv.x * dv; acc.y = xv.y * dv; acc.z = xv.z * dv; acc.w = xv.w * dv;
    int s = off[v], e = off[v + 1];
    for (int j = s; j < e; ++j) {
        int2 p = epack[j];
        int r = p.x;
        float w = __int_as_float(p.y);
        float4 xr = *(const float4*)&x[(size_t)r * DIM + f];
        acc.x += xr.x * w; acc.y += xr.y * w; acc.z += xr.z * w; acc.w += xr.w * w;
    }
    acc.x *= dv; acc.y *= dv; acc.z *= dv; acc.w *= dv;
    size_t base = (size_t)v * DIM + f;
    if (MODE == 0) {
        float4 bv = *(const float4*)&bias[f];
        acc.x = fmaxf(acc.x + bv.x, 0.f);
        acc.y = fmaxf(acc.y + bv.y, 0.f);
        acc.z = fmaxf(acc.z + bv.z, 0.f);
        acc.w = fmaxf(acc.w + bv.w, 0.f);
        *(float4*)&outf[base] = acc;
    } else {
        float a[4] = {acc.x, acc.y, acc.z, acc.w};
        ushort4v hv, lv;
#pragma unroll
        for (int i = 0; i < 4; ++i) {
            unsigned short h = f2bf(a[i]);
            hv[i] = h;
            lv[i] = f2bf(a[i] - bf2f(h));
        }
        *(ushort4v*)&outh[base] = hv;
        *(ushort4v*)&outl[base] = lv;
    }
}

// ---------------------------------------------------------------------------
// split-bf16 MFMA GEMM: C[M,N] = (Ah+Al)[M,K] @ (Bh+Bl)[K,N] (+bias)(relu)
// B passed pre-transposed as [N][K]. 128x128 tile, BK=32, 4 waves, each wave
// computes a 64x64 quadrant as 4x4 frags of 16x16x32. 3 MFMAs per frag pair
// (hh + hl + lh); residual ~2^-18 relative => fp32-equivalent accuracy.
template <int BIAS, int RELU, int SPLIT_OUT>
__global__ __launch_bounds__(256) void k_gemm_mfma(
    const unsigned short* __restrict__ Ah, const unsigned short* __restrict__ Al,
    const unsigned short* __restrict__ Bh, const unsigned short* __restrict__ Bl,
    const float* __restrict__ bias, float* __restrict__ Cf,
    unsigned short* __restrict__ Ch, unsigned short* __restrict__ Cl,
    int M, int K, int N) {
    __shared__ unsigned short AsH[128 * 32], AsL[128 * 32];
    __shared__ unsigned short BsH[128 * 32], BsL[128 * 32];
    int tid = threadIdx.x;
    int lane = tid & 63;
    int w = tid >> 6;
    int wr = w & 1, wc = w >> 1;
    int bm = blockIdx.x * 128, bn = blockIdx.y * 128;

    floatx4 acc[4][4];
    floatx4 zero = {0.f, 0.f, 0.f, 0.f};
#pragma unroll
    for (int t = 0; t < 4; ++t)
#pragma unroll
        for (int u = 0; u < 4; ++u) acc[t][u] = zero;

    // staging: wave w covers chunks c0,c1 (16 rows x 32 k each);
    // lane l -> row c*16 + l/4, k-offset (l%4)*8
    int c0 = w * 2, c1 = c0 + 1;
    int srow = lane >> 2;
    int kc = (lane & 3) * 8;
    int ar0 = bm + c0 * 16 + srow; if (ar0 >= M) ar0 = M - 1;
    int ar1 = bm + c1 * 16 + srow; if (ar1 >= M) ar1 = M - 1;
    int br0 = bn + c0 * 16 + srow;
    int br1 = bn + c1 * 16 + srow;

    int fr = lane & 15;   // row/col within a 16-tile
    int fq = lane >> 4;   // k-block (0..3), 8 elems each

    for (int k0 = 0; k0 < K; k0 += 32) {
        __syncthreads();  // previous tile fully consumed
        gload16(Ah + (size_t)ar0 * K + k0 + kc, AsH + c0 * 512);
        gload16(Ah + (size_t)ar1 * K + k0 + kc, AsH + c1 * 512);
        gload16(Al + (size_t)ar0 * K + k0 + kc, AsL + c0 * 512);
        gload16(Al + (size_t)ar1 * K + k0 + kc, AsL + c1 * 512);
        gload16(Bh + (size_t)br0 * K + k0 + kc, BsH + c0 * 512);
        gload16(Bh + (size_t)br1 * K + k0 + kc, BsH + c1 * 512);
        gload16(Bl + (size_t)br0 * K + k0 + kc, BsL + c0 * 512);
        gload16(Bl + (size_t)br1 * K + k0 + kc, BsL + c1 * 512);
        __syncthreads();  // drains vmcnt + barrier

        short8 ah[4], al[4], bh[4], bl[4];
#pragma unroll
        for (int t = 0; t < 4; ++t) {
            int ra = (wr * 64 + t * 16 + fr) * 32 + fq * 8;
            ah[t] = *(const short8*)&AsH[ra];
            al[t] = *(const short8*)&AsL[ra];
            int rb = (wc * 64 + t * 16 + fr) * 32 + fq * 8;
            bh[t] = *(const short8*)&BsH[rb];
            bl[t] = *(const short8*)&BsL[rb];
        }
#pragma unroll
        for (int t = 0; t < 4; ++t)
#pragma unroll
            for (int u = 0; u < 4; ++u) {
                acc[t][u] = __builtin_amdgcn_mfma_f32_16x16x32_bf16(ah[t], bh[u], acc[t][u], 0, 0, 0);
                acc[t][u] = __builtin_amdgcn_mfma_f32_16x16x32_bf16(ah[t], bl[u], acc[t][u], 0, 0, 0);
                acc[t][u] = __builtin_amdgcn_mfma_f32_16x16x32_bf16(al[t], bh[u], acc[t][u], 0, 0, 0);
            }
    }

    // epilogue: C/D layout col = lane&15, row = (lane>>4)*4 + reg
#pragma unroll
    for (int u = 0; u < 4; ++u) {
        int colg = bn + wc * 64 + u * 16 + fr;
        float bv = BIAS ? bias[colg] : 0.0f;
#pragma unroll
        for (int t = 0; t < 4; ++t) {
#pragma unroll
            for (int r = 0; r < 4; ++r) {
                int rowg = bm + wr * 64 + t * 16 + fq * 4 + r;
                if (rowg < M) {
                    float o = acc[t][u][r] + bv;
                    if (RELU) o = fmaxf(o, 0.f);
                    size_t idx = (size_t)rowg * N + colg;
                    if (SPLIT_OUT) {
                        unsigned short h = f2bf(o);
                        Ch[idx] = h;
                        Cl[idx] = f2bf(o - bf2f(h));
                    } else {
                        Cf[idx] = o;
                    }
                }
            }
        }
    }
}

// column partial-sums of h3 [N_NODES x 256] into g
__global__ void k_colsum(const float* __restrict__ h, float* __restrict__ g) {
    int c = threadIdx.x;
    int r0 = blockIdx.x * 256;
    int r1 = r0 + 256; if (r1 > N_NODES) r1 = N_NODES;
    float acc = 0.0f;
    for (int r = r0; r < r1; ++r) acc += h[(size_t)r * 256 + c];
    atomicAdd(&g[c], acc);
}

__global__ void k_mlp(const float* __restrict__ g,
                      const float* __restrict__ Wf1, const float* __restrict__ bf1,
                      const float* __restrict__ Wf2, const float* __restrict__ bf2,
                      const float* __restrict__ Wf3, const float* __restrict__ bf3,
                      float* __restrict__ out) {
    __shared__ float s0[256], s1[128], s2[64];
    int t = threadIdx.x;
    s0[t] = g[t] * (1.0f / (float)N_NODES);
    __syncthreads();
    if (t < 128) {
        float a = bf1[t];
        for (int k = 0; k < 256; ++k) a += s0[k] * Wf1[k * 128 + t];
        s1[t] = fmaxf(a, 0.0f);
    }
    __syncthreads();
    if (t < 64) {
        float a = bf2[t];
        for (int k = 0; k < 128; ++k) a += s1[k] * Wf2[k * 64 + t];
        s2[t] = fmaxf(a, 0.0f);
    }
    __syncthreads();
    if (t == 0) {
        float a = bf3[0];
        for (int k = 0; k < 64; ++k) a += s2[k] * Wf3[k];
        out[0] = a;
    }
}

extern "C" void kernel_launch(void* const* d_in, const int* in_sizes, int n_in,
                              void* d_out, int out_size, void* d_ws, size_t ws_size,
                              hipStream_t stream) {
    const float* x  = (const float*)d_in[0];
    const int* ei   = (const int*)d_in[1];
    const float* W1 = (const float*)d_in[2];
    const float* b1 = (const float*)d_in[3];
    const float* W2 = (const float*)d_in[4];
    const float* b2 = (const float*)d_in[5];
    const float* W3 = (const float*)d_in[6];
    const float* b3 = (const float*)d_in[7];
    const float* Wf1 = (const float*)d_in[8];
    const float* bf1 = (const float*)d_in[9];
    const float* Wf2 = (const float*)d_in[10];
    const float* bf2 = (const float*)d_in[11];
    const float* Wf3 = (const float*)d_in[12];
    const float* bf3 = (const float*)d_in[13];
    float* out = (float*)d_out;

    char* p = (char*)d_ws;
    auto alloc = [&](size_t bytes) {
        void* r = (void*)p;
        p += (bytes + 255) & ~((size_t)255);
        return r;
    };
    int*   cnt    = (int*)  alloc(N_NODES * sizeof(int));
    int*   off    = (int*)  alloc((N_NODES + 1) * sizeof(int));
    int*   cursor = (int*)  alloc(N_NODES * sizeof(int));
    float* dinv   = (float*)alloc(N_NODES * sizeof(float));
    int2*  epack  = (int2*) alloc((size_t)N_EDGES * sizeof(int2));
    float* g      = (float*)alloc(256 * sizeof(float));
    // split weights (transposed [N][K])
    unsigned short* W1h = (unsigned short*)alloc(128 * 256 * 2);
    unsigned short* W1l = (unsigned short*)alloc(128 * 256 * 2);
    unsigned short* W2h = (unsigned short*)alloc(256 * 512 * 2);
    unsigned short* W2l = (unsigned short*)alloc(256 * 512 * 2);
    unsigned short* W3h = (unsigned short*)alloc(512 * 256 * 2);
    unsigned short* W3l = (unsigned short*)alloc(512 * 256 * 2);
    // activations (regions reused across lifetimes):
    unsigned short* t0h = (unsigned short*)alloc((size_t)N_NODES * 128 * 2); // A1
    unsigned short* t0l = (unsigned short*)alloc((size_t)N_NODES * 128 * 2);
    char* A2 = (char*)alloc((size_t)N_NODES * 512 * 2);  // h1 fp32 -> h2h bf16
    char* A3 = (char*)alloc((size_t)N_NODES * 256 * 4);  // t1h+t1l -> t2 fp32
    char* A4 = (char*)alloc((size_t)N_NODES * 512 * 2);  // h2l -> h3 fp32... (h3=51.2MB == A4 size)
    float* h1          = (float*)A2;
    unsigned short* h2h = (unsigned short*)A2;
    unsigned short* t1h = (unsigned short*)A3;
    unsigned short* t1l = (unsigned short*)(A3 + (size_t)N_NODES * 256 * 2);
    float* t2          = (float*)A3;
    unsigned short* h2l = (unsigned short*)A4;
    float* h3          = (float*)A4;

    const int* row = ei;
    const int* col = ei + N_EDGES;

    const int NB = (N_NODES + 255) / 256;
    const int EB = (N_EDGES + 255) / 256;

    // CSR build + norm
    k_init<<<NB, 256, 0, stream>>>(cnt, g);
    k_count<<<EB, 256, 0, stream>>>(col, cnt);
    k_dinv<<<NB, 256, 0, stream>>>(cnt, dinv);
    k_scan<<<1, 1024, 0, stream>>>(cnt, off, cursor);
    k_fill<<<EB, 256, 0, stream>>>(row, col, dinv, cursor, epack);

    // weight prep (transpose + split)
    k_prepW<<<(128 * 256 + 255) / 256, 256, 0, stream>>>(W1, W1h, W1l, 128, 256);
    k_prepW<<<(256 * 512 + 255) / 256, 256, 0, stream>>>(W2, W2h, W2l, 256, 512);
    k_prepW<<<(512 * 256 + 255) / 256, 256, 0, stream>>>(W3, W3h, W3l, 512, 256);

    const int M = N_NODES;
    const int MB = (M + 127) / 128; // 391

    // conv1: t0 = agg(x) -> split; h1 = relu(t0@W1 + b1) fp32
    k_agg4<128, 1><<<(N_NODES + 7) / 8, 256, 0, stream>>>(
        x, off, epack, dinv, nullptr, nullptr, t0h, t0l, N_NODES);
    {
        dim3 grid(MB, 256 / 128);
        k_gemm_mfma<1, 1, 0><<<grid, 256, 0, stream>>>(
            t0h, t0l, W1h, W1l, b1, h1, nullptr, nullptr, M, 128, 256);
    }
    // conv2: t1 = agg(h1) -> split; h2 = relu(t1@W2 + b2) -> split
    k_agg4<256, 1><<<(N_NODES + 3) / 4, 256, 0, stream>>>(
        h1, off, epack, dinv, nullptr, nullptr, t1h, t1l, N_NODES);
    {
        dim3 grid(MB, 512 / 128);
        k_gemm_mfma<1, 1, 1><<<grid, 256, 0, stream>>>(
            t1h, t1l, W2h, W2l, b2, nullptr, h2h, h2l, M, 256, 512);
    }
    // conv3: t2 = h2@W3 fp32; h3 = relu(agg(t2) + b3) fp32
    {
        dim3 grid(MB, 256 / 128);
        k_gemm_mfma<0, 0, 0><<<grid, 256, 0, stream>>>(
            h2h, h2l, W3h, W3l, nullptr, t2, nullptr, nullptr, M, 512, 256);
    }
    k_agg4<256, 0><<<(N_NODES + 3) / 4, 256, 0, stream>>>(
        t2, off, epack, dinv, b3, h3, nullptr, nullptr, N_NODES);

    // pooling + MLP
    k_colsum<<<NB, 256, 0, stream>>>(h3, g);
    k_mlp<<<1, 256, 0, stream>>>(g, Wf1, bf1, Wf2, bf2, Wf3, bf3, out);
}